// Round 7
// baseline (1788.610 us; speedup 1.0000x reference)
//
#include <hip/hip_runtime.h>
#include <cmath>

#ifndef M_PI
#define M_PI 3.14159265358979323846
#endif

#define K_CHEB 48
#define A_CHEB 0.05
#define B_CHEB 14.0
#define PS_S 7
#define PS_Q 6

typedef __attribute__((ext_vector_type(8))) short bhalf8;
typedef __attribute__((ext_vector_type(16))) float f32x16;

struct PSArg {
  float mid, invhalf;
  float a[PS_Q + 1][PS_S];   // a[q][r]
};

// ---------- bf16 split helpers ----------

// packed RNE f32->bf16: lo16 = bf16(a), hi16 = bf16(b). One VALU op.
__device__ __forceinline__ unsigned cvt_pk_bf16(float a, float b) {
  unsigned r;
  asm("v_cvt_pk_bf16_f32 %0, %1, %2" : "=v"(r) : "v"(a), "v"(b));
  return r;
}

// split 4 floats into bf16 hi/lo pairs and store 8B each to LDS.
__device__ __forceinline__ void split4_store(short* __restrict__ Xh, short* __restrict__ Xl,
                                             int off, float v0, float v1, float v2, float v3) {
  unsigned h01 = cvt_pk_bf16(v0, v1);
  unsigned h23 = cvt_pk_bf16(v2, v3);
  float r0 = v0 - __uint_as_float(h01 << 16);
  float r1 = v1 - __uint_as_float(h01 & 0xffff0000u);
  float r2 = v2 - __uint_as_float(h23 << 16);
  float r3 = v3 - __uint_as_float(h23 & 0xffff0000u);
  unsigned l01 = cvt_pk_bf16(r0, r1);
  unsigned l23 = cvt_pk_bf16(r2, r3);
  *(uint2*)(Xh + off) = make_uint2(h01, h23);
  *(uint2*)(Xl + off) = make_uint2(l01, l23);
}

// ---------- generic fp32 LDS helpers (small single-matrix kernels) ----------

__device__ __forceinline__ void stage64(const float* __restrict__ g, float* __restrict__ s, int tid) {
#pragma unroll
  for (int r = 0; r < 4; r++) {
    int idx = tid + 256 * r;
    *(float4*)(s + 4 * idx) = *(const float4*)(g + 4 * idx);
  }
}

__device__ __forceinline__ void store_tile(float* __restrict__ S, int r0, int c0, const float t[16]) {
#pragma unroll
  for (int i = 0; i < 4; i++)
    *(float4*)(S + (r0 + i) * 64 + c0) = *(const float4*)(&t[4 * i]);
}

// C = A^T B (== A*B for symmetric A). Row-wise float4 LDS reads.
__device__ __forceinline__ void gemm_tile_sym(const float* __restrict__ A, const float* __restrict__ B,
                                              int r0, int c0, float t[16]) {
#pragma unroll
  for (int i = 0; i < 16; i++) t[i] = 0.f;
#pragma unroll 4
  for (int k = 0; k < 64; k += 4) {
    float a[16], b[16];
#pragma unroll
    for (int kk = 0; kk < 4; kk++) {
      *(float4*)(&a[4 * kk]) = *(const float4*)(A + (k + kk) * 64 + r0);
      *(float4*)(&b[4 * kk]) = *(const float4*)(B + (k + kk) * 64 + c0);
    }
#pragma unroll
    for (int kk = 0; kk < 4; kk++)
#pragma unroll
      for (int i = 0; i < 4; i++)
#pragma unroll
        for (int j = 0; j < 4; j++)
          t[4 * i + j] += a[4 * kk + i] * b[4 * kk + j];
  }
}

// trace/64 of a 64x64 LDS matrix, broadcast to all threads (each wave redundantly)
__device__ __forceinline__ float trace_bcast(const float* __restrict__ s) {
  const int l = threadIdx.x & 63;
  float d = s[l * 65];
#pragma unroll
  for (int o = 32; o > 0; o >>= 1) d += __shfl_down(d, o, 64);
  return __shfl(d, 0, 64) * (1.f / 64.f);
}

// ---------- batch mean ----------

__global__ __launch_bounds__(256) void reduce_mean8(const float* __restrict__ data,
                                                    float* __restrict__ part) {
  const size_t base = (size_t)blockIdx.x * 8 * 4096;
  const int tid = threadIdx.x;
#pragma unroll
  for (int r = 0; r < 4; r++) {
    int idx = tid + 256 * r;
    float4 s = make_float4(0.f, 0.f, 0.f, 0.f);
#pragma unroll
    for (int m = 0; m < 8; m++) {
      float4 v = *(const float4*)(data + base + (size_t)m * 4096 + 4 * idx);
      s.x += v.x; s.y += v.y; s.z += v.z; s.w += v.w;
    }
    *(float4*)(part + (size_t)blockIdx.x * 4096 + 4 * idx) = s;
  }
}

// 64 blocks; block handles 64 columns, 4-way split over the parts dimension.
__global__ __launch_bounds__(256) void reduce_cols(const float* __restrict__ part,
                                                   float* __restrict__ outv,
                                                   int nparts, float scale) {
  __shared__ float s[3][64];
  const int jj = threadIdx.x & 63, gg = threadIdx.x >> 6;
  const int j = (blockIdx.x << 6) + jj;
  float sum = 0.f;
  for (int g = gg; g < nparts; g += 4)
    sum += part[(size_t)g * 4096 + j];
  if (gg) s[gg - 1][jj] = sum;
  __syncthreads();
  if (gg == 0) outv[j] = (sum + s[0][jj] + s[1][jj] + s[2][jj]) * scale;
}

// ---------- the hot kernel: per-batch logm via MFMA + Paterson-Stockmeyer ----------
//
// v7 = v6 (T2-composition chain, 12 barrier phases/matrix, pad-72, 4 LDS
// buffers, 2 blocks/CU, scalarized elementwise w/ dsel) + two prod3 changes:
//  (a) 2 independent MFMA accumulator chains (dep chain 12 -> 6+6 parallel;
//      round-4 proved no spill at VGPR=128/FETCH=71MB)
//  (b) s_setprio(1) around the MFMA cluster (2 resident blocks at different
//      phases -> scheduler has real arbitration; first clean test)
// DO NOT: f32x16 whole-vector elementwise or dg vector (round-3 spills);
// min-waves-3 bound (round-2 spills); XOR swizzle (round-4, more conflicts).

#define LDX 72   // padded row stride; 144 B -> 16B-aligned frags
#define MAT (64 * LDX)

__device__ __forceinline__ void load_afrags(const short* __restrict__ Xh, const short* __restrict__ Xl,
                                            int aoff, bhalf8 ah[4], bhalf8 al[4]) {
#pragma unroll
  for (int kb = 0; kb < 4; kb++) {
    ah[kb] = *(const bhalf8*)(Xh + aoff + 16 * kb);
    al[kb] = *(const bhalf8*)(Xl + aoff + 16 * kb);
  }
}

__device__ __forceinline__ f32x16 prod3(const bhalf8 ah[4], const bhalf8 al[4],
                                        const short* __restrict__ Bh, const short* __restrict__ Bl,
                                        int boff) {
  f32x16 a0, a1;
#pragma unroll
  for (int t = 0; t < 16; t++) { a0[t] = 0.f; a1[t] = 0.f; }
  __builtin_amdgcn_s_setprio(1);
#pragma unroll
  for (int kb = 0; kb < 4; kb++) {
    bhalf8 bh = *(const bhalf8*)(Bh + boff + 16 * kb);
    bhalf8 bl = *(const bhalf8*)(Bl + boff + 16 * kb);
    if (kb & 1) {
      a1 = __builtin_amdgcn_mfma_f32_32x32x16_bf16(ah[kb], bh, a1, 0, 0, 0);
      a1 = __builtin_amdgcn_mfma_f32_32x32x16_bf16(ah[kb], bl, a1, 0, 0, 0);
      a1 = __builtin_amdgcn_mfma_f32_32x32x16_bf16(al[kb], bh, a1, 0, 0, 0);
    } else {
      a0 = __builtin_amdgcn_mfma_f32_32x32x16_bf16(ah[kb], bh, a0, 0, 0, 0);
      a0 = __builtin_amdgcn_mfma_f32_32x32x16_bf16(ah[kb], bl, a0, 0, 0, 0);
      a0 = __builtin_amdgcn_mfma_f32_32x32x16_bf16(al[kb], bh, a0, 0, 0, 0);
    }
  }
  __builtin_amdgcn_s_setprio(0);
  return a0 + a1;
}

// write v^T (hi/lo bf16) into X: X[n][m] = v[m][n]; n = bcol, m = 32R+8g+4*half+t
__device__ __forceinline__ void tstore16(short* __restrict__ Xh, short* __restrict__ Xl,
                                         int bcol, int R, int half, const f32x16 v) {
#pragma unroll
  for (int g = 0; g < 4; g++) {
    int off = bcol * LDX + 32 * R + 8 * g + 4 * half;
    split4_store(Xh, Xl, off, v[4 * g + 0], v[4 * g + 1], v[4 * g + 2], v[4 * g + 3]);
  }
}

// stage a row-major 64x64 fp32 matrix into bf16 hi/lo LDS
__device__ __forceinline__ void stage_split(const float* __restrict__ g64,
                                            short* __restrict__ Xh, short* __restrict__ Xl,
                                            int tid) {
#pragma unroll
  for (int i = 0; i < 4; i++) {
    int idx = tid + 256 * i;
    float4 v = *(const float4*)(g64 + 4 * idx);
    int row = idx >> 4, col = (idx & 15) << 2;
    split4_store(Xh, Xl, row * LDX + col, v.x, v.y, v.z, v.w);
  }
}

__global__ __launch_bounds__(256, 2) void cheb_ps(const float* __restrict__ data,
                                                  const float* __restrict__ Mi,
                                                  float* __restrict__ partial,
                                                  PSArg co) {
  extern __shared__ __align__(16) short smem[];
  short* s0h = smem;            short* s0l = s0h + MAT;
  short* s1h = s0l + MAT;       short* s1l = s1h + MAT;
  short* s2h = s1l + MAT;       short* s2l = s2h + MAT;
  short* s3h = s2l + MAT;       short* s3l = s3h + MAT;

  const int tid = threadIdx.x;
  const int lane = tid & 63, wv = tid >> 6;
  const int R = wv >> 1, C = wv & 1;
  const int ln31 = lane & 31, half = lane >> 5;
  const int aoff = (32 * R + ln31) * LDX + half * 8;   // A-frag element offset (+16*kb)
  const int bcol = 32 * C + ln31;
  const int boff = bcol * LDX + half * 8;              // B-frag element offset (+16*kb)
  // D-layout row of acc element (4g+t) is 32R+8g+4half+t; diagonal when == bcol:
  const int dsel = bcol - 32 * R - 4 * half;           // diag iff 8*g + t == dsel

  f32x16 accTm;
#pragma unroll
  for (int t = 0; t < 16; t++) accTm[t] = 0.f;

  bhalf8 ah[4], al[4];

#pragma unroll 1
  for (int m = 0; m < 8; m++) {
    // stage: D -> s0, Mi -> s1 (both buffers dead at this point; see q=1 barrier)
    stage_split(data + ((size_t)blockIdx.x * 8 + m) * 4096, s0h, s0l, tid);
    stage_split(Mi, s1h, s1l, tid);
    __syncthreads();

    // P1: V = D*Mi -> s2
    load_afrags(s0h, s0l, aoff, ah, al);                 // A = D
    f32x16 acc = prod3(ah, al, s1h, s1l, boff);          // B = Mi
    tstore16(s2h, s2l, bcol, R, half, acc);
    __syncthreads();

    // P2: W = Mi*V -> What -> s3
    load_afrags(s1h, s1l, aoff, ah, al);                 // A = Mi
    acc = prod3(ah, al, s2h, s2l, boff);                 // B = V
    f32x16 T1;
#pragma unroll
    for (int g = 0; g < 4; g++)
#pragma unroll
      for (int t = 0; t < 4; t++) {
        float a = acc[4 * g + t];
        if (8 * g + t == dsel) a -= co.mid;
        T1[4 * g + t] = a * co.invhalf;
      }
    tstore16(s3h, s3l, bcol, R, half, T1);
    __syncthreads();

    // T2 = 2*What*What - I -> s0  (D dead)
    load_afrags(s3h, s3l, aoff, ah, al);                 // A = What
    acc = prod3(ah, al, s3h, s3l, boff);                 // B = What
    f32x16 T2;
#pragma unroll
    for (int g = 0; g < 4; g++)
#pragma unroll
      for (int t = 0; t < 4; t++)
        T2[4 * g + t] = 2.f * acc[4 * g + t] - ((8 * g + t == dsel) ? 1.f : 0.f);
    tstore16(s0h, s0l, bcol, R, half, T2);
    __syncthreads();

    // {T3, T4}: A = T2 for the remainder of the chain (loaded once)
    load_afrags(s0h, s0l, aoff, ah, al);                 // A = T2
    acc          = prod3(ah, al, s3h, s3l, boff);        // B = What  -> T3
    f32x16 acc2  = prod3(ah, al, s0h, s0l, boff);        // B = T2    -> T4
    f32x16 T3, T4;
#pragma unroll
    for (int t = 0; t < 16; t++) T3[t] = 2.f * acc[t] - T1[t];
#pragma unroll
    for (int g = 0; g < 4; g++)
#pragma unroll
      for (int t = 0; t < 4; t++)
        T4[4 * g + t] = 2.f * acc2[4 * g + t] - ((8 * g + t == dsel) ? 1.f : 0.f);
    tstore16(s2h, s2l, bcol, R, half, T3);               // V dead
    tstore16(s1h, s1l, bcol, R, half, T4);               // Mi dead (re-staged next matrix)
    __syncthreads();

    // {T5, T6}: T5 = 2*T2*T3 - T1 ; T6 = 2*T2*T4 - T2 (T6 kept in regs only)
    acc  = prod3(ah, al, s2h, s2l, boff);                // B = T3
    acc2 = prod3(ah, al, s1h, s1l, boff);                // B = T4
    f32x16 T5, T6;
#pragma unroll
    for (int t = 0; t < 16; t++) T5[t] = 2.f * acc[t] - T1[t];
#pragma unroll
    for (int t = 0; t < 16; t++) T6[t] = 2.f * acc2[t] - T2[t];
    tstore16(s3h, s3l, bcol, R, half, T5);               // What dead
    __syncthreads();

    // T7: Y = 2*T2*T5 - T3 -> s1 (T4 dead); Clenshaw init bq1 = G6 -> s0 (T2 LDS dead)
    acc = prod3(ah, al, s3h, s3l, boff);                 // B = T5
    f32x16 Y7;
#pragma unroll
    for (int t = 0; t < 16; t++) Y7[t] = 2.f * acc[t] - T3[t];
    tstore16(s1h, s1l, bcol, R, half, Y7);
    f32x16 bq1, bq2;
#pragma unroll
    for (int g = 0; g < 4; g++)
#pragma unroll
      for (int t = 0; t < 4; t++) {
        int i = 4 * g + t;
        float v = co.a[6][1] * T1[i] + co.a[6][2] * T2[i] + co.a[6][3] * T3[i]
                + co.a[6][4] * T4[i] + co.a[6][5] * T5[i] + co.a[6][6] * T6[i];
        if (8 * g + t == dsel) v += co.a[6][0];
        bq1[i] = v; bq2[i] = 0.f;
      }
    tstore16(s0h, s0l, bcol, R, half, bq1);
    __syncthreads();

    load_afrags(s1h, s1l, aoff, ah, al);                 // A = Y
    // q = 5..1: odd q reads s0 writes s2; even q reads s2 writes s0
#pragma unroll
    for (int q = 5; q >= 1; q--) {
      const short* rh = (q & 1) ? s0h : s2h;
      const short* rl = (q & 1) ? s0l : s2l;
      short* wh = (q & 1) ? s2h : s0h;
      short* wl = (q & 1) ? s2l : s0l;
      acc = prod3(ah, al, rh, rl, boff);
      f32x16 nb;
#pragma unroll
      for (int g = 0; g < 4; g++)
#pragma unroll
        for (int t = 0; t < 4; t++) {
          int i = 4 * g + t;
          float gq = co.a[q][1] * T1[i] + co.a[q][2] * T2[i] + co.a[q][3] * T3[i]
                   + co.a[q][4] * T4[i] + co.a[q][5] * T5[i] + co.a[q][6] * T6[i];
          if (8 * g + t == dsel) gq += co.a[q][0];
          nb[i] = gq + 2.f * acc[i] - bq2[i];
        }
      bq2 = bq1; bq1 = nb;
      tstore16(wh, wl, bcol, R, half, bq1);
      __syncthreads();
    }

    // final: Y*b1 (b1 in s2; q=1 wrote s2). No barrier needed before next stage:
    // stage writes s0/s1 whose last reads completed before the q=1 barrier,
    // and the barrier after stage orders these s2 reads vs P1's s2 write.
    acc = prod3(ah, al, s2h, s2l, boff);
#pragma unroll
    for (int g = 0; g < 4; g++)
#pragma unroll
      for (int t = 0; t < 4; t++) {
        int i = 4 * g + t;
        float g0 = co.a[0][1] * T1[i] + co.a[0][2] * T2[i] + co.a[0][3] * T3[i]
                 + co.a[0][4] * T4[i] + co.a[0][5] * T5[i] + co.a[0][6] * T6[i];
        if (8 * g + t == dsel) g0 += co.a[0][0];
        accTm[i] += g0 + acc[i] - bq2[i];
      }
  }

  // write block-partial sum of logs (D-layout scatter; once per block)
  float* pp = partial + (size_t)blockIdx.x * 4096;
#pragma unroll
  for (int g = 0; g < 4; g++)
#pragma unroll
    for (int t = 0; t < 4; t++)
      pp[(32 * R + 8 * g + 4 * half + t) * 64 + bcol] = accTm[4 * g + t];
}

// ---------- single-matrix sqrt/invsqrt via binomial series ----------

__global__ __launch_bounds__(256) void invsqrt_series(const float* __restrict__ Min,
                                                      float* __restrict__ MiOut,
                                                      float* __restrict__ MsOut) {
  __shared__ float sM[4096], sE[4096], sE2[4096], sE3[4096];
  const int tid = threadIdx.x;
  const int r0 = (tid >> 4) << 2, c0 = (tid & 15) << 2;

  stage64(Min, sM, tid);
  __syncthreads();
  const float csh = trace_bcast(sM);
  const float invc = 1.f / csh;
  for (int idx = tid; idx < 4096; idx += 256) {
    int r = idx >> 6, c = idx & 63;
    sE[idx] = 0.5f * (sM[idx] + sM[c * 64 + r]) * invc - ((r == c) ? 1.f : 0.f);
  }
  __syncthreads();

  float t[16];
  gemm_tile_sym(sE, sE, r0, c0, t);  store_tile(sE2, r0, c0, t); __syncthreads();
  gemm_tile_sym(sE2, sE, r0, c0, t); store_tile(sE3, r0, c0, t); __syncthreads();
  gemm_tile_sym(sE2, sE2, r0, c0, t); store_tile(sM, r0, c0, t); __syncthreads();
  float t5[16];
  gemm_tile_sym(sE2, sE3, r0, c0, t5);

  const float sc = sqrtf(csh), rsc = 1.f / sc;
#pragma unroll
  for (int i = 0; i < 4; i++)
#pragma unroll
    for (int j = 0; j < 4; j++) {
      int off = (r0 + i) * 64 + (c0 + j);
      float d = ((r0 + i) == (c0 + j)) ? 1.f : 0.f;
      float e = sE[off], e2 = sE2[off], e3 = sE3[off], e4 = sM[off], e5 = t5[4 * i + j];
      float mi = (d - 0.5f * e + 0.375f * e2 - 0.3125f * e3 + 0.2734375f * e4 - 0.24609375f * e5) * rsc;
      float ms = (d + 0.5f * e - 0.125f * e2 + 0.0625f * e3 - 0.0390625f * e4 + 0.02734375f * e5) * sc;
      MiOut[off] = mi;
      MsOut[off] = ms;
    }
}

// ---------- Taylor-8 expm ----------

__device__ void taylor_expm8(const float* __restrict__ sA, float* __restrict__ sR,
                             int tid, int r0, int c0, float postscale) {
  for (int idx = tid; idx < 4096; idx += 256) {
    int r = idx >> 6, c = idx & 63;
    sR[idx] = ((r == c) ? 1.f : 0.f) + sA[idx] * 0.125f;
  }
  __syncthreads();
  float t[16];
#pragma unroll 1
  for (int k = 7; k >= 1; k--) {
    gemm_tile_sym(sA, sR, r0, c0, t);
    __syncthreads();
    const float inv = 1.f / (float)k;
    const float fin = (k == 1) ? postscale : 1.f;
#pragma unroll
    for (int i = 0; i < 4; i++)
#pragma unroll
      for (int j = 0; j < 4; j++) {
        int off = (r0 + i) * 64 + (c0 + j);
        float d = ((r0 + i) == (c0 + j)) ? 1.f : 0.f;
        sR[off] = (d + t[4 * i + j] * inv) * fin;
      }
    __syncthreads();
  }
}

// ---------- fused: M = Ms*expm(sym(Tm))*Ms ; then {Mi, Ms} = invsqrt/sqrt(M) ----------

__global__ __launch_bounds__(256) void expm_invsqrt(const float* __restrict__ Tin,
                                                    const float* __restrict__ Msin,
                                                    float* __restrict__ MiOut,
                                                    float* __restrict__ MsOut) {
  __shared__ float s0[4096], s1[4096], s2[4096], s3[4096], s4[4096];
  const int tid = threadIdx.x;
  const int r0 = (tid >> 4) << 2, c0 = (tid & 15) << 2;
  float t[16];

  // ---- expm part ----
  stage64(Tin, s0, tid);
  __syncthreads();
  const float mu = trace_bcast(s0);
  for (int idx = tid; idx < 4096; idx += 256) {
    int r = idx >> 6, c = idx & 63;
    s1[idx] = 0.5f * (s0[idx] + s0[c * 64 + r]) - ((r == c) ? mu : 0.f);
  }
  __syncthreads();
  taylor_expm8(s1, s2, tid, r0, c0, expf(mu));      // s2 = R = expm(sym(Tm)-mu I)*e^mu

  stage64(Msin, s0, tid);
  __syncthreads();
  gemm_tile_sym(s2, s0, r0, c0, t);                 // R*Ms
  store_tile(s3, r0, c0, t);
  __syncthreads();
  gemm_tile_sym(s0, s3, r0, c0, t);                 // M = Ms*(R*Ms)
  store_tile(s4, r0, c0, t);
  __syncthreads();

  // ---- invsqrt part on M (s4) ----
  const float csh = trace_bcast(s4);
  const float invc = 1.f / csh;
  for (int idx = tid; idx < 4096; idx += 256) {
    int r = idx >> 6, c = idx & 63;
    s0[idx] = 0.5f * (s4[idx] + s4[c * 64 + r]) * invc - ((r == c) ? 1.f : 0.f);
  }
  __syncthreads();
  gemm_tile_sym(s0, s0, r0, c0, t);  store_tile(s1, r0, c0, t); __syncthreads();  // E2
  gemm_tile_sym(s1, s0, r0, c0, t);  store_tile(s2, r0, c0, t); __syncthreads();  // E3
  gemm_tile_sym(s1, s1, r0, c0, t);  store_tile(s3, r0, c0, t); __syncthreads();  // E4
  float t5[16];
  gemm_tile_sym(s1, s2, r0, c0, t5);                                              // E5

  const float sc = sqrtf(csh), rsc = 1.f / sc;
#pragma unroll
  for (int i = 0; i < 4; i++)
#pragma unroll
    for (int j = 0; j < 4; j++) {
      int off = (r0 + i) * 64 + (c0 + j);
      float d = ((r0 + i) == (c0 + j)) ? 1.f : 0.f;
      float e = s0[off], e2 = s1[off], e3 = s2[off], e4 = s3[off], e5 = t5[4 * i + j];
      float mi = (d - 0.5f * e + 0.375f * e2 - 0.3125f * e3 + 0.2734375f * e4 - 0.24609375f * e5) * rsc;
      float ms = (d + 0.5f * e - 0.125f * e2 + 0.0625f * e3 - 0.0390625f * e4 + 0.02734375f * e5) * sc;
      MiOut[off] = mi;
      MsOut[off] = ms;
    }
}

__global__ __launch_bounds__(256) void bias_expm_P(const float* __restrict__ bias,
                                                   const float* __restrict__ Gin,
                                                   float* __restrict__ Pout) {
  __shared__ float sA[4096], sR[4096], sB[4096];
  const int tid = threadIdx.x;
  const int r0 = (tid >> 4) << 2, c0 = (tid & 15) << 2;

  stage64(bias, sB, tid);
  __syncthreads();
  for (int idx = tid; idx < 4096; idx += 256) {
    int r = idx >> 6, c = idx & 63;
    sA[idx] = 0.0625f * (sB[idx] + sB[c * 64 + r]);
  }
  __syncthreads();
  taylor_expm8(sA, sR, tid, r0, c0, 1.f);

  float t[16];
  gemm_tile_sym(sR, sR, r0, c0, t);
  store_tile(sB, r0, c0, t);
  __syncthreads();
  gemm_tile_sym(sB, sB, r0, c0, t);
  store_tile(sR, r0, c0, t);
  stage64(Gin, sA, tid);
  __syncthreads();
  gemm_tile_sym(sR, sA, r0, c0, t);
#pragma unroll
  for (int i = 0; i < 4; i++)
    *(float4*)(Pout + (r0 + i) * 64 + c0) = *(const float4*)(&t[4 * i]);
}

__global__ __launch_bounds__(256) void final_out(const float* __restrict__ data,
                                                 const float* __restrict__ Pin,
                                                 float* __restrict__ out) {
  __shared__ float sPT[4096], sD[4096], sT[4096];
  const int tid = threadIdx.x;
  const int r0 = (tid >> 4) << 2, c0 = (tid & 15) << 2;

  for (int idx = tid; idx < 4096; idx += 256) {
    int r = idx >> 6, c = idx & 63;
    sPT[c * 64 + r] = Pin[idx];
  }
  __syncthreads();
  float t[16];
#pragma unroll 1
  for (int m = 0; m < 8; m++) {
    size_t b = (size_t)blockIdx.x * 8 + m;
    stage64(data + b * 4096, sD, tid);
    __syncthreads();
    gemm_tile_sym(sD, sPT, r0, c0, t);
    store_tile(sT, r0, c0, t);
    __syncthreads();
    gemm_tile_sym(sPT, sT, r0, c0, t);
    float* ob = out + b * 4096;
#pragma unroll
    for (int i = 0; i < 4; i++)
      *(float4*)(ob + (r0 + i) * 64 + c0) = *(const float4*)(&t[4 * i]);
    __syncthreads();
  }
}

// ---------- launch ----------

extern "C" void kernel_launch(void* const* d_in, const int* in_sizes, int n_in,
                              void* d_out, int out_size, void* d_ws, size_t ws_size,
                              hipStream_t stream) {
  const float* data = (const float*)d_in[0];
  const float* bias = (const float*)d_in[1];
  float* out = (float*)d_out;

  float* part = out;                 // partial scratch inside d_out
  float* M  = (float*)d_ws;
  float* Mi = M + 4096;
  float* Ms = Mi + 4096;
  float* Tm = Ms + 4096;
  float* P  = Tm + 4096;

  // 72 KB dynamic LDS for cheb_ps (2 blocks/CU: 144 KB of 160 KB)
  static bool attr_done = false;
  if (!attr_done) {
    hipFuncSetAttribute(reinterpret_cast<const void*>(cheb_ps),
                        hipFuncAttributeMaxDynamicSharedMemorySize,
                        8 * MAT * (int)sizeof(short));
    attr_done = true;
  }
  const int lds_bytes = 8 * MAT * (int)sizeof(short);

  // Chebyshev coefficients of log on [a,b], then exact Paterson-Stockmeyer
  // re-factoring: sum_k c_k T_k = sum_q [sum_r a_qr T_r] T_q(T_s), s=7, Q=6.
  PSArg co;
  {
    const double a = A_CHEB, b = B_CHEB;
    const int N = 256;
    double c[64] = {0};
    for (int j = 0; j <= K_CHEB; j++) {
      double s = 0.0;
      for (int k = 0; k < N; k++) {
        double th = M_PI * (k + 0.5) / N;
        double x = 0.5 * (a + b) + 0.5 * (b - a) * std::cos(th);
        s += std::log(x) * std::cos(j * th);
      }
      c[j] = 2.0 * s / N;
    }
    c[0] *= 0.5;                     // plain sum convention
    double aa[PS_Q + 1][PS_S] = {};
    for (int q = PS_Q; q >= 1; --q) {
      for (int r = PS_S - 1; r >= 1; --r) {
        int k = q * PS_S + r;
        double av = 2.0 * c[k];
        aa[q][r] = av;
        c[k] -= av * 0.5;            // -> 0
        c[q * PS_S - r] -= av * 0.5; // reflection T_r*T_qs = (T_qs+r + T_qs-r)/2
      }
      aa[q][0] = c[q * PS_S];
      c[q * PS_S] = 0.0;
    }
    for (int r = 0; r < PS_S; r++) aa[0][r] = c[r];
    co.mid = (float)(0.5 * (a + b));
    co.invhalf = (float)(2.0 / (b - a));
    for (int q = 0; q <= PS_Q; q++)
      for (int r = 0; r < PS_S; r++) co.a[q][r] = (float)aa[q][r];
  }

  reduce_mean8<<<1024, 256, 0, stream>>>(data, part);
  reduce_cols<<<64, 256, 0, stream>>>(part, M, 1024, 1.f / 8192.f);
  invsqrt_series<<<1, 256, 0, stream>>>(M, Mi, Ms);

  for (int it = 0; it < 3; ++it) {
    cheb_ps<<<1024, 256, lds_bytes, stream>>>(data, Mi, part, co);
    reduce_cols<<<64, 256, 0, stream>>>(part, Tm, 1024, 1.f / 8192.f);
    expm_invsqrt<<<1, 256, 0, stream>>>(Tm, Ms, Mi, Ms);   // last iter: Mi = G
  }

  bias_expm_P<<<1, 256, 0, stream>>>(bias, Mi, P);
  final_out<<<1024, 256, 0, stream>>>(data, P, out);
}

// Round 8
// 1592.039 us; speedup vs baseline: 1.1235x; 1.1235x over previous
//
#include <hip/hip_runtime.h>
#include <cmath>

#ifndef M_PI
#define M_PI 3.14159265358979323846
#endif

#define K_CHEB 48
#define A_CHEB 0.05
#define B_CHEB 14.0
#define PS_S 7
#define PS_Q 6

typedef __attribute__((ext_vector_type(8))) short bhalf8;
typedef __attribute__((ext_vector_type(16))) float f32x16;

struct PSArg {
  float mid, invhalf;
  float a[PS_Q + 1][PS_S];   // a[q][r]
};

// ---------- bf16 split helpers ----------

// packed RNE f32->bf16: lo16 = bf16(a), hi16 = bf16(b). One VALU op.
__device__ __forceinline__ unsigned cvt_pk_bf16(float a, float b) {
  unsigned r;
  asm("v_cvt_pk_bf16_f32 %0, %1, %2" : "=v"(r) : "v"(a), "v"(b));
  return r;
}

// split 4 floats into bf16 hi/lo pairs and store 8B each to LDS.
__device__ __forceinline__ void split4_store(short* __restrict__ Xh, short* __restrict__ Xl,
                                             int off, float v0, float v1, float v2, float v3) {
  unsigned h01 = cvt_pk_bf16(v0, v1);
  unsigned h23 = cvt_pk_bf16(v2, v3);
  float r0 = v0 - __uint_as_float(h01 << 16);
  float r1 = v1 - __uint_as_float(h01 & 0xffff0000u);
  float r2 = v2 - __uint_as_float(h23 << 16);
  float r3 = v3 - __uint_as_float(h23 & 0xffff0000u);
  unsigned l01 = cvt_pk_bf16(r0, r1);
  unsigned l23 = cvt_pk_bf16(r2, r3);
  *(uint2*)(Xh + off) = make_uint2(h01, h23);
  *(uint2*)(Xl + off) = make_uint2(l01, l23);
}

// ---------- generic fp32 LDS helpers ----------

// 512-thread staging: 2 float4 per thread
__device__ __forceinline__ void stage64_512(const float* __restrict__ g, float* __restrict__ s, int tid) {
#pragma unroll
  for (int r = 0; r < 2; r++) {
    int idx = tid + 512 * r;
    *(float4*)(s + 4 * idx) = *(const float4*)(g + 4 * idx);
  }
}

__device__ __forceinline__ void stage64(const float* __restrict__ g, float* __restrict__ s, int tid) {
#pragma unroll
  for (int r = 0; r < 4; r++) {
    int idx = tid + 256 * r;
    *(float4*)(s + 4 * idx) = *(const float4*)(g + 4 * idx);
  }
}

__device__ __forceinline__ void store_tile_2r(float* __restrict__ S, int r0, int c0, const float t[8]) {
#pragma unroll
  for (int i = 0; i < 2; i++)
    *(float4*)(S + (r0 + i) * 64 + c0) = *(const float4*)(&t[4 * i]);
}

// C = A^T B (== A*B for symmetric A). 512-thread version: 2x4 tile per thread.
// Same per-element k/kk FMA order as the old 4x4 version -> bit-identical.
__device__ __forceinline__ void gemm_tile_sym_2r(const float* __restrict__ A, const float* __restrict__ B,
                                                 int r0, int c0, float t[8]) {
#pragma unroll
  for (int i = 0; i < 8; i++) t[i] = 0.f;
#pragma unroll 4
  for (int k = 0; k < 64; k += 4) {
    float a[8], b[16];
#pragma unroll
    for (int kk = 0; kk < 4; kk++) {
      *(float2*)(&a[2 * kk]) = *(const float2*)(A + (k + kk) * 64 + r0);
      *(float4*)(&b[4 * kk]) = *(const float4*)(B + (k + kk) * 64 + c0);
    }
#pragma unroll
    for (int kk = 0; kk < 4; kk++)
#pragma unroll
      for (int i = 0; i < 2; i++)
#pragma unroll
        for (int j = 0; j < 4; j++)
          t[4 * i + j] += a[2 * kk + i] * b[4 * kk + j];
  }
}

// trace/64 of a 64x64 LDS matrix, broadcast (each wave redundantly)
__device__ __forceinline__ float trace_bcast(const float* __restrict__ s) {
  const int l = threadIdx.x & 63;
  float d = s[l * 65];
#pragma unroll
  for (int o = 32; o > 0; o >>= 1) d += __shfl_down(d, o, 64);
  return __shfl(d, 0, 64) * (1.f / 64.f);
}

// ---------- batch mean ----------

__global__ __launch_bounds__(256) void reduce_mean8(const float* __restrict__ data,
                                                    float* __restrict__ part) {
  const size_t base = (size_t)blockIdx.x * 8 * 4096;
  const int tid = threadIdx.x;
#pragma unroll
  for (int r = 0; r < 4; r++) {
    int idx = tid + 256 * r;
    float4 s = make_float4(0.f, 0.f, 0.f, 0.f);
#pragma unroll
    for (int m = 0; m < 8; m++) {
      float4 v = *(const float4*)(data + base + (size_t)m * 4096 + 4 * idx);
      s.x += v.x; s.y += v.y; s.z += v.z; s.w += v.w;
    }
    *(float4*)(part + (size_t)blockIdx.x * 4096 + 4 * idx) = s;
  }
}

// 64 blocks; block handles 64 columns, 4-way split over the parts dimension.
__global__ __launch_bounds__(256) void reduce_cols(const float* __restrict__ part,
                                                   float* __restrict__ outv,
                                                   int nparts, float scale) {
  __shared__ float s[3][64];
  const int jj = threadIdx.x & 63, gg = threadIdx.x >> 6;
  const int j = (blockIdx.x << 6) + jj;
  float sum = 0.f;
  for (int g = gg; g < nparts; g += 4)
    sum += part[(size_t)g * 4096 + j];
  if (gg) s[gg - 1][jj] = sum;
  __syncthreads();
  if (gg == 0) outv[j] = (sum + s[0][jj] + s[1][jj] + s[2][jj]) * scale;
}

// ---------- the hot kernel: per-batch logm via MFMA + Paterson-Stockmeyer ----------
//
// v8 = v6 (T2-composition chain, 12 barrier phases/matrix, pad-72, 4 LDS
// buffers, 2 blocks/CU, scalarized elementwise w/ dsel, SINGLE-chain prod3)
// + setprio(1) around the MFMA cluster only (zero register delta; clean test).
// DO NOT (hardened over rounds 2,3,4,7):
//  - 2-acc prod3 on this structure (round-7: acc+acc2 already live in paired
//    phases; +16 AGPR spills -> FETCH 80->357MB, dur +52%)
//  - f32x16 whole-vector elementwise or dg vector (round-3 spills)
//  - min-waves-3 launch bound (round-2 spills)
//  - XOR swizzle (round-4: more conflicts, and conflicts are off-critical-path)

#define LDX 72   // padded row stride; 144 B -> 16B-aligned frags
#define MAT (64 * LDX)

__device__ __forceinline__ void load_afrags(const short* __restrict__ Xh, const short* __restrict__ Xl,
                                            int aoff, bhalf8 ah[4], bhalf8 al[4]) {
#pragma unroll
  for (int kb = 0; kb < 4; kb++) {
    ah[kb] = *(const bhalf8*)(Xh + aoff + 16 * kb);
    al[kb] = *(const bhalf8*)(Xl + aoff + 16 * kb);
  }
}

__device__ __forceinline__ f32x16 prod3(const bhalf8 ah[4], const bhalf8 al[4],
                                        const short* __restrict__ Bh, const short* __restrict__ Bl,
                                        int boff) {
  f32x16 acc;
#pragma unroll
  for (int t = 0; t < 16; t++) acc[t] = 0.f;
  __builtin_amdgcn_s_setprio(1);
#pragma unroll
  for (int kb = 0; kb < 4; kb++) {
    bhalf8 bh = *(const bhalf8*)(Bh + boff + 16 * kb);
    bhalf8 bl = *(const bhalf8*)(Bl + boff + 16 * kb);
    acc = __builtin_amdgcn_mfma_f32_32x32x16_bf16(ah[kb], bh, acc, 0, 0, 0);
    acc = __builtin_amdgcn_mfma_f32_32x32x16_bf16(ah[kb], bl, acc, 0, 0, 0);
    acc = __builtin_amdgcn_mfma_f32_32x32x16_bf16(al[kb], bh, acc, 0, 0, 0);
  }
  __builtin_amdgcn_s_setprio(0);
  return acc;
}

// write v^T (hi/lo bf16) into X: X[n][m] = v[m][n]; n = bcol, m = 32R+8g+4*half+t
__device__ __forceinline__ void tstore16(short* __restrict__ Xh, short* __restrict__ Xl,
                                         int bcol, int R, int half, const f32x16 v) {
#pragma unroll
  for (int g = 0; g < 4; g++) {
    int off = bcol * LDX + 32 * R + 8 * g + 4 * half;
    split4_store(Xh, Xl, off, v[4 * g + 0], v[4 * g + 1], v[4 * g + 2], v[4 * g + 3]);
  }
}

// stage a row-major 64x64 fp32 matrix into bf16 hi/lo LDS
__device__ __forceinline__ void stage_split(const float* __restrict__ g64,
                                            short* __restrict__ Xh, short* __restrict__ Xl,
                                            int tid) {
#pragma unroll
  for (int i = 0; i < 4; i++) {
    int idx = tid + 256 * i;
    float4 v = *(const float4*)(g64 + 4 * idx);
    int row = idx >> 4, col = (idx & 15) << 2;
    split4_store(Xh, Xl, row * LDX + col, v.x, v.y, v.z, v.w);
  }
}

__global__ __launch_bounds__(256, 2) void cheb_ps(const float* __restrict__ data,
                                                  const float* __restrict__ Mi,
                                                  float* __restrict__ partial,
                                                  PSArg co) {
  extern __shared__ __align__(16) short smem[];
  short* s0h = smem;            short* s0l = s0h + MAT;
  short* s1h = s0l + MAT;       short* s1l = s1h + MAT;
  short* s2h = s1l + MAT;       short* s2l = s2h + MAT;
  short* s3h = s2l + MAT;       short* s3l = s3h + MAT;

  const int tid = threadIdx.x;
  const int lane = tid & 63, wv = tid >> 6;
  const int R = wv >> 1, C = wv & 1;
  const int ln31 = lane & 31, half = lane >> 5;
  const int aoff = (32 * R + ln31) * LDX + half * 8;   // A-frag element offset (+16*kb)
  const int bcol = 32 * C + ln31;
  const int boff = bcol * LDX + half * 8;              // B-frag element offset (+16*kb)
  // D-layout row of acc element (4g+t) is 32R+8g+4half+t; diagonal when == bcol:
  const int dsel = bcol - 32 * R - 4 * half;           // diag iff 8*g + t == dsel

  f32x16 accTm;
#pragma unroll
  for (int t = 0; t < 16; t++) accTm[t] = 0.f;

  bhalf8 ah[4], al[4];

#pragma unroll 1
  for (int m = 0; m < 8; m++) {
    // stage: D -> s0, Mi -> s1 (both buffers dead at this point; see q=1 barrier)
    stage_split(data + ((size_t)blockIdx.x * 8 + m) * 4096, s0h, s0l, tid);
    stage_split(Mi, s1h, s1l, tid);
    __syncthreads();

    // P1: V = D*Mi -> s2
    load_afrags(s0h, s0l, aoff, ah, al);                 // A = D
    f32x16 acc = prod3(ah, al, s1h, s1l, boff);          // B = Mi
    tstore16(s2h, s2l, bcol, R, half, acc);
    __syncthreads();

    // P2: W = Mi*V -> What -> s3
    load_afrags(s1h, s1l, aoff, ah, al);                 // A = Mi
    acc = prod3(ah, al, s2h, s2l, boff);                 // B = V
    f32x16 T1;
#pragma unroll
    for (int g = 0; g < 4; g++)
#pragma unroll
      for (int t = 0; t < 4; t++) {
        float a = acc[4 * g + t];
        if (8 * g + t == dsel) a -= co.mid;
        T1[4 * g + t] = a * co.invhalf;
      }
    tstore16(s3h, s3l, bcol, R, half, T1);
    __syncthreads();

    // T2 = 2*What*What - I -> s0  (D dead)
    load_afrags(s3h, s3l, aoff, ah, al);                 // A = What
    acc = prod3(ah, al, s3h, s3l, boff);                 // B = What
    f32x16 T2;
#pragma unroll
    for (int g = 0; g < 4; g++)
#pragma unroll
      for (int t = 0; t < 4; t++)
        T2[4 * g + t] = 2.f * acc[4 * g + t] - ((8 * g + t == dsel) ? 1.f : 0.f);
    tstore16(s0h, s0l, bcol, R, half, T2);
    __syncthreads();

    // {T3, T4}: A = T2 for the remainder of the chain (loaded once)
    load_afrags(s0h, s0l, aoff, ah, al);                 // A = T2
    acc          = prod3(ah, al, s3h, s3l, boff);        // B = What  -> T3
    f32x16 acc2  = prod3(ah, al, s0h, s0l, boff);        // B = T2    -> T4
    f32x16 T3, T4;
#pragma unroll
    for (int t = 0; t < 16; t++) T3[t] = 2.f * acc[t] - T1[t];
#pragma unroll
    for (int g = 0; g < 4; g++)
#pragma unroll
      for (int t = 0; t < 4; t++)
        T4[4 * g + t] = 2.f * acc2[4 * g + t] - ((8 * g + t == dsel) ? 1.f : 0.f);
    tstore16(s2h, s2l, bcol, R, half, T3);               // V dead
    tstore16(s1h, s1l, bcol, R, half, T4);               // Mi dead (re-staged next matrix)
    __syncthreads();

    // {T5, T6}: T5 = 2*T2*T3 - T1 ; T6 = 2*T2*T4 - T2 (T6 kept in regs only)
    acc  = prod3(ah, al, s2h, s2l, boff);                // B = T3
    acc2 = prod3(ah, al, s1h, s1l, boff);                // B = T4
    f32x16 T5, T6;
#pragma unroll
    for (int t = 0; t < 16; t++) T5[t] = 2.f * acc[t] - T1[t];
#pragma unroll
    for (int t = 0; t < 16; t++) T6[t] = 2.f * acc2[t] - T2[t];
    tstore16(s3h, s3l, bcol, R, half, T5);               // What dead
    __syncthreads();

    // T7: Y = 2*T2*T5 - T3 -> s1 (T4 dead); Clenshaw init bq1 = G6 -> s0 (T2 LDS dead)
    acc = prod3(ah, al, s3h, s3l, boff);                 // B = T5
    f32x16 Y7;
#pragma unroll
    for (int t = 0; t < 16; t++) Y7[t] = 2.f * acc[t] - T3[t];
    tstore16(s1h, s1l, bcol, R, half, Y7);
    f32x16 bq1, bq2;
#pragma unroll
    for (int g = 0; g < 4; g++)
#pragma unroll
      for (int t = 0; t < 4; t++) {
        int i = 4 * g + t;
        float v = co.a[6][1] * T1[i] + co.a[6][2] * T2[i] + co.a[6][3] * T3[i]
                + co.a[6][4] * T4[i] + co.a[6][5] * T5[i] + co.a[6][6] * T6[i];
        if (8 * g + t == dsel) v += co.a[6][0];
        bq1[i] = v; bq2[i] = 0.f;
      }
    tstore16(s0h, s0l, bcol, R, half, bq1);
    __syncthreads();

    load_afrags(s1h, s1l, aoff, ah, al);                 // A = Y
    // q = 5..1: odd q reads s0 writes s2; even q reads s2 writes s0
#pragma unroll
    for (int q = 5; q >= 1; q--) {
      const short* rh = (q & 1) ? s0h : s2h;
      const short* rl = (q & 1) ? s0l : s2l;
      short* wh = (q & 1) ? s2h : s0h;
      short* wl = (q & 1) ? s2l : s0l;
      acc = prod3(ah, al, rh, rl, boff);
      f32x16 nb;
#pragma unroll
      for (int g = 0; g < 4; g++)
#pragma unroll
        for (int t = 0; t < 4; t++) {
          int i = 4 * g + t;
          float gq = co.a[q][1] * T1[i] + co.a[q][2] * T2[i] + co.a[q][3] * T3[i]
                   + co.a[q][4] * T4[i] + co.a[q][5] * T5[i] + co.a[q][6] * T6[i];
          if (8 * g + t == dsel) gq += co.a[q][0];
          nb[i] = gq + 2.f * acc[i] - bq2[i];
        }
      bq2 = bq1; bq1 = nb;
      tstore16(wh, wl, bcol, R, half, bq1);
      __syncthreads();
    }

    // final: Y*b1 (b1 in s2; q=1 wrote s2). No barrier needed before next stage:
    // stage writes s0/s1 whose last reads completed before the q=1 barrier,
    // and the barrier after stage orders these s2 reads vs P1's s2 write.
    acc = prod3(ah, al, s2h, s2l, boff);
#pragma unroll
    for (int g = 0; g < 4; g++)
#pragma unroll
      for (int t = 0; t < 4; t++) {
        int i = 4 * g + t;
        float g0 = co.a[0][1] * T1[i] + co.a[0][2] * T2[i] + co.a[0][3] * T3[i]
                 + co.a[0][4] * T4[i] + co.a[0][5] * T5[i] + co.a[0][6] * T6[i];
        if (8 * g + t == dsel) g0 += co.a[0][0];
        accTm[i] += g0 + acc[i] - bq2[i];
      }
  }

  // write block-partial sum of logs (D-layout scatter; once per block)
  float* pp = partial + (size_t)blockIdx.x * 4096;
#pragma unroll
  for (int g = 0; g < 4; g++)
#pragma unroll
    for (int t = 0; t < 4; t++)
      pp[(32 * R + 8 * g + 4 * half + t) * 64 + bcol] = accTm[4 * g + t];
}

// ---------- single-matrix sqrt/invsqrt via binomial series (512 threads) ----------

__global__ __launch_bounds__(512) void invsqrt_series(const float* __restrict__ Min,
                                                      float* __restrict__ MiOut,
                                                      float* __restrict__ MsOut) {
  __shared__ float sM[4096], sE[4096], sE2[4096], sE3[4096];
  const int tid = threadIdx.x;
  const int r0 = (tid >> 4) << 1, c0 = (tid & 15) << 2;   // 2x4 tile

  stage64_512(Min, sM, tid);
  __syncthreads();
  const float csh = trace_bcast(sM);
  const float invc = 1.f / csh;
  for (int idx = tid; idx < 4096; idx += 512) {
    int r = idx >> 6, c = idx & 63;
    sE[idx] = 0.5f * (sM[idx] + sM[c * 64 + r]) * invc - ((r == c) ? 1.f : 0.f);
  }
  __syncthreads();

  float t[8];
  gemm_tile_sym_2r(sE, sE, r0, c0, t);   store_tile_2r(sE2, r0, c0, t); __syncthreads();
  gemm_tile_sym_2r(sE2, sE, r0, c0, t);  store_tile_2r(sE3, r0, c0, t); __syncthreads();
  gemm_tile_sym_2r(sE2, sE2, r0, c0, t); store_tile_2r(sM, r0, c0, t);  __syncthreads();
  float t5[8];
  gemm_tile_sym_2r(sE2, sE3, r0, c0, t5);

  const float sc = sqrtf(csh), rsc = 1.f / sc;
#pragma unroll
  for (int i = 0; i < 2; i++)
#pragma unroll
    for (int j = 0; j < 4; j++) {
      int off = (r0 + i) * 64 + (c0 + j);
      float d = ((r0 + i) == (c0 + j)) ? 1.f : 0.f;
      float e = sE[off], e2 = sE2[off], e3 = sE3[off], e4 = sM[off], e5 = t5[4 * i + j];
      float mi = (d - 0.5f * e + 0.375f * e2 - 0.3125f * e3 + 0.2734375f * e4 - 0.24609375f * e5) * rsc;
      float ms = (d + 0.5f * e - 0.125f * e2 + 0.0625f * e3 - 0.0390625f * e4 + 0.02734375f * e5) * sc;
      MiOut[off] = mi;
      MsOut[off] = ms;
    }
}

// ---------- Taylor-8 expm (512 threads) ----------

__device__ void taylor_expm8_2r(const float* __restrict__ sA, float* __restrict__ sR,
                                int tid, int r0, int c0, float postscale) {
  for (int idx = tid; idx < 4096; idx += 512) {
    int r = idx >> 6, c = idx & 63;
    sR[idx] = ((r == c) ? 1.f : 0.f) + sA[idx] * 0.125f;
  }
  __syncthreads();
  float t[8];
#pragma unroll 1
  for (int k = 7; k >= 1; k--) {
    gemm_tile_sym_2r(sA, sR, r0, c0, t);
    __syncthreads();
    const float inv = 1.f / (float)k;
    const float fin = (k == 1) ? postscale : 1.f;
#pragma unroll
    for (int i = 0; i < 2; i++)
#pragma unroll
      for (int j = 0; j < 4; j++) {
        int off = (r0 + i) * 64 + (c0 + j);
        float d = ((r0 + i) == (c0 + j)) ? 1.f : 0.f;
        sR[off] = (d + t[4 * i + j] * inv) * fin;
      }
    __syncthreads();
  }
}

// ---------- fused: M = Ms*expm(sym(Tm))*Ms ; then {Mi, Ms} = invsqrt/sqrt(M) ----------

__global__ __launch_bounds__(512) void expm_invsqrt(const float* __restrict__ Tin,
                                                    const float* __restrict__ Msin,
                                                    float* __restrict__ MiOut,
                                                    float* __restrict__ MsOut) {
  __shared__ float s0[4096], s1[4096], s2[4096], s3[4096], s4[4096];
  const int tid = threadIdx.x;
  const int r0 = (tid >> 4) << 1, c0 = (tid & 15) << 2;   // 2x4 tile
  float t[8];

  // ---- expm part ----
  stage64_512(Tin, s0, tid);
  __syncthreads();
  const float mu = trace_bcast(s0);
  for (int idx = tid; idx < 4096; idx += 512) {
    int r = idx >> 6, c = idx & 63;
    s1[idx] = 0.5f * (s0[idx] + s0[c * 64 + r]) - ((r == c) ? mu : 0.f);
  }
  __syncthreads();
  taylor_expm8_2r(s1, s2, tid, r0, c0, expf(mu));   // s2 = R = expm(sym(Tm)-mu I)*e^mu

  stage64_512(Msin, s0, tid);
  __syncthreads();
  gemm_tile_sym_2r(s2, s0, r0, c0, t);              // R*Ms
  store_tile_2r(s3, r0, c0, t);
  __syncthreads();
  gemm_tile_sym_2r(s0, s3, r0, c0, t);              // M = Ms*(R*Ms)
  store_tile_2r(s4, r0, c0, t);
  __syncthreads();

  // ---- invsqrt part on M (s4) ----
  const float csh = trace_bcast(s4);
  const float invc = 1.f / csh;
  for (int idx = tid; idx < 4096; idx += 512) {
    int r = idx >> 6, c = idx & 63;
    s0[idx] = 0.5f * (s4[idx] + s4[c * 64 + r]) * invc - ((r == c) ? 1.f : 0.f);
  }
  __syncthreads();
  gemm_tile_sym_2r(s0, s0, r0, c0, t);  store_tile_2r(s1, r0, c0, t); __syncthreads();  // E2
  gemm_tile_sym_2r(s1, s0, r0, c0, t);  store_tile_2r(s2, r0, c0, t); __syncthreads();  // E3
  gemm_tile_sym_2r(s1, s1, r0, c0, t);  store_tile_2r(s3, r0, c0, t); __syncthreads();  // E4
  float t5[8];
  gemm_tile_sym_2r(s1, s2, r0, c0, t5);                                                 // E5

  const float sc = sqrtf(csh), rsc = 1.f / sc;
#pragma unroll
  for (int i = 0; i < 2; i++)
#pragma unroll
    for (int j = 0; j < 4; j++) {
      int off = (r0 + i) * 64 + (c0 + j);
      float d = ((r0 + i) == (c0 + j)) ? 1.f : 0.f;
      float e = s0[off], e2 = s1[off], e3 = s2[off], e4 = s3[off], e5 = t5[4 * i + j];
      float mi = (d - 0.5f * e + 0.375f * e2 - 0.3125f * e3 + 0.2734375f * e4 - 0.24609375f * e5) * rsc;
      float ms = (d + 0.5f * e - 0.125f * e2 + 0.0625f * e3 - 0.0390625f * e4 + 0.02734375f * e5) * sc;
      MiOut[off] = mi;
      MsOut[off] = ms;
    }
}

__global__ __launch_bounds__(512) void bias_expm_P(const float* __restrict__ bias,
                                                   const float* __restrict__ Gin,
                                                   float* __restrict__ Pout) {
  __shared__ float sA[4096], sR[4096], sB[4096];
  const int tid = threadIdx.x;
  const int r0 = (tid >> 4) << 1, c0 = (tid & 15) << 2;   // 2x4 tile

  stage64_512(bias, sB, tid);
  __syncthreads();
  for (int idx = tid; idx < 4096; idx += 512) {
    int r = idx >> 6, c = idx & 63;
    sA[idx] = 0.0625f * (sB[idx] + sB[c * 64 + r]);
  }
  __syncthreads();
  taylor_expm8_2r(sA, sR, tid, r0, c0, 1.f);

  float t[8];
  gemm_tile_sym_2r(sR, sR, r0, c0, t);
  store_tile_2r(sB, r0, c0, t);
  __syncthreads();
  gemm_tile_sym_2r(sB, sB, r0, c0, t);
  store_tile_2r(sR, r0, c0, t);
  stage64_512(Gin, sA, tid);
  __syncthreads();
  gemm_tile_sym_2r(sR, sA, r0, c0, t);
#pragma unroll
  for (int i = 0; i < 2; i++)
    *(float4*)(Pout + (r0 + i) * 64 + c0) = *(const float4*)(&t[4 * i]);
}

__global__ __launch_bounds__(256) void final_out(const float* __restrict__ data,
                                                 const float* __restrict__ Pin,
                                                 float* __restrict__ out) {
  __shared__ float sPT[4096], sD[4096], sT[4096];
  const int tid = threadIdx.x;
  const int r0 = (tid >> 4) << 2, c0 = (tid & 15) << 2;

  for (int idx = tid; idx < 4096; idx += 256) {
    int r = idx >> 6, c = idx & 63;
    sPT[c * 64 + r] = Pin[idx];
  }
  __syncthreads();
  float t[16];
#pragma unroll 1
  for (int m = 0; m < 8; m++) {
    size_t b = (size_t)blockIdx.x * 8 + m;
    stage64(data + b * 4096, sD, tid);
    __syncthreads();
    // C = A^T B 4x4 tile (256-thread path, unchanged from v6)
#pragma unroll
    for (int i = 0; i < 16; i++) t[i] = 0.f;
#pragma unroll 4
    for (int k = 0; k < 64; k += 4) {
      float a[16], bb[16];
#pragma unroll
      for (int kk = 0; kk < 4; kk++) {
        *(float4*)(&a[4 * kk])  = *(const float4*)(sD + (k + kk) * 64 + r0);
        *(float4*)(&bb[4 * kk]) = *(const float4*)(sPT + (k + kk) * 64 + c0);
      }
#pragma unroll
      for (int kk = 0; kk < 4; kk++)
#pragma unroll
        for (int i = 0; i < 4; i++)
#pragma unroll
          for (int j = 0; j < 4; j++)
            t[4 * i + j] += a[4 * kk + i] * bb[4 * kk + j];
    }
#pragma unroll
    for (int i = 0; i < 4; i++)
      *(float4*)(sT + (r0 + i) * 64 + c0) = *(const float4*)(&t[4 * i]);
    __syncthreads();
#pragma unroll
    for (int i = 0; i < 16; i++) t[i] = 0.f;
#pragma unroll 4
    for (int k = 0; k < 64; k += 4) {
      float a[16], bb[16];
#pragma unroll
      for (int kk = 0; kk < 4; kk++) {
        *(float4*)(&a[4 * kk])  = *(const float4*)(sPT + (k + kk) * 64 + r0);
        *(float4*)(&bb[4 * kk]) = *(const float4*)(sT + (k + kk) * 64 + c0);
      }
#pragma unroll
      for (int kk = 0; kk < 4; kk++)
#pragma unroll
        for (int i = 0; i < 4; i++)
#pragma unroll
          for (int j = 0; j < 4; j++)
            t[4 * i + j] += a[4 * kk + i] * bb[4 * kk + j];
    }
    float* ob = out + b * 4096;
#pragma unroll
    for (int i = 0; i < 4; i++)
      *(float4*)(ob + (r0 + i) * 64 + c0) = *(const float4*)(&t[4 * i]);
    __syncthreads();
  }
}

// ---------- launch ----------

extern "C" void kernel_launch(void* const* d_in, const int* in_sizes, int n_in,
                              void* d_out, int out_size, void* d_ws, size_t ws_size,
                              hipStream_t stream) {
  const float* data = (const float*)d_in[0];
  const float* bias = (const float*)d_in[1];
  float* out = (float*)d_out;

  float* part = out;                 // partial scratch inside d_out
  float* M  = (float*)d_ws;
  float* Mi = M + 4096;
  float* Ms = Mi + 4096;
  float* Tm = Ms + 4096;
  float* P  = Tm + 4096;

  // 72 KB dynamic LDS for cheb_ps (2 blocks/CU: 144 KB of 160 KB)
  static bool attr_done = false;
  if (!attr_done) {
    hipFuncSetAttribute(reinterpret_cast<const void*>(cheb_ps),
                        hipFuncAttributeMaxDynamicSharedMemorySize,
                        8 * MAT * (int)sizeof(short));
    attr_done = true;
  }
  const int lds_bytes = 8 * MAT * (int)sizeof(short);

  // Chebyshev coefficients of log on [a,b], then exact Paterson-Stockmeyer
  // re-factoring: sum_k c_k T_k = sum_q [sum_r a_qr T_r] T_q(T_s), s=7, Q=6.
  PSArg co;
  {
    const double a = A_CHEB, b = B_CHEB;
    const int N = 256;
    double c[64] = {0};
    for (int j = 0; j <= K_CHEB; j++) {
      double s = 0.0;
      for (int k = 0; k < N; k++) {
        double th = M_PI * (k + 0.5) / N;
        double x = 0.5 * (a + b) + 0.5 * (b - a) * std::cos(th);
        s += std::log(x) * std::cos(j * th);
      }
      c[j] = 2.0 * s / N;
    }
    c[0] *= 0.5;                     // plain sum convention
    double aa[PS_Q + 1][PS_S] = {};
    for (int q = PS_Q; q >= 1; --q) {
      for (int r = PS_S - 1; r >= 1; --r) {
        int k = q * PS_S + r;
        double av = 2.0 * c[k];
        aa[q][r] = av;
        c[k] -= av * 0.5;            // -> 0
        c[q * PS_S - r] -= av * 0.5; // reflection T_r*T_qs = (T_qs+r + T_qs-r)/2
      }
      aa[q][0] = c[q * PS_S];
      c[q * PS_S] = 0.0;
    }
    for (int r = 0; r < PS_S; r++) aa[0][r] = c[r];
    co.mid = (float)(0.5 * (a + b));
    co.invhalf = (float)(2.0 / (b - a));
    for (int q = 0; q <= PS_Q; q++)
      for (int r = 0; r < PS_S; r++) co.a[q][r] = (float)aa[q][r];
  }

  reduce_mean8<<<1024, 256, 0, stream>>>(data, part);
  reduce_cols<<<64, 256, 0, stream>>>(part, M, 1024, 1.f / 8192.f);
  invsqrt_series<<<1, 512, 0, stream>>>(M, Mi, Ms);

  for (int it = 0; it < 3; ++it) {
    cheb_ps<<<1024, 256, lds_bytes, stream>>>(data, Mi, part, co);
    reduce_cols<<<64, 256, 0, stream>>>(part, Tm, 1024, 1.f / 8192.f);
    expm_invsqrt<<<1, 512, 0, stream>>>(Tm, Ms, Mi, Ms);   // last iter: Mi = G
  }

  bias_expm_P<<<1, 512, 0, stream>>>(bias, Mi, P);
  final_out<<<1024, 256, 0, stream>>>(data, P, out);
}